// Round 4
// baseline (454.393 us; speedup 1.0000x reference)
//
#include <hip/hip_runtime.h>
#include <math.h>

#define NOBJ 8
#define NP   65536
#define NM   32
#define ND   128
#define PTS_WG   512          // points per block (4 waves x 128)
#define PTS_WAVE 128
#define CHUNKS   (NP / PTS_WG)   // 128 -> grid 1024 = 4 blocks/CU resident

__device__ __forceinline__ unsigned f2bf(float f) {   // fp32 -> bf16 bits, RNE
  unsigned u = __float_as_uint(f);
  return (u + 0x7FFFu + ((u >> 16) & 1u)) >> 16;
}

// sum_sq = A + B - 2C with A=sum m*||x||^2, B=sum cnt*||e||^2, C=sum e.(m x)
// C via per-group (4 masks) nibble subset-sum table, bf16-packed:
//   Tu[g*1024 + n*64 + s], s=(p&1)*32+(p>>1), p=dim-pair -> lane c reads
//   s=c and s=c+32 (both bank c: conflict-free).
__launch_bounds__(256, 4)
__global__ void distill_main(const float* __restrict__ net,
                             const float* __restrict__ embs,
                             const int* __restrict__ mask,
                             float* __restrict__ ws) {
  __shared__ unsigned Tu[8 * 16 * 64];   // 32 KB
  __shared__ float esq[NM];
  __shared__ int   Wlds[4 * PTS_WAVE];   // 2 KB
  __shared__ float red[4][4];

  const int tid  = threadIdx.x;
  const int wave = tid >> 6;
  const int lane = tid & 63;
  const int o     = blockIdx.x >> 7;
  const int chunk = blockIdx.x & (CHUNKS - 1);

  const float* EB = embs + (size_t)o * NM * ND;

  // ---- esq[m] = sum_d clean(e)^2 (fp32 exact) ----
  if (tid < NM) {
    float a = 0.f;
    const float* e = EB + (size_t)tid * ND;
    for (int d_ = 0; d_ < ND; ++d_) {
      float v = e[d_];
      if (!isfinite(v)) v = 0.f;
      a += v * v;
    }
    esq[tid] = a;
  }

  // ---- build bf16 nibble subset-sum table ----
  for (int it = 0; it < 32; ++it) {
    int idx = it * 256 + tid;            // g*1024 + n*64 + s
    int s = idx & 63, n = (idx >> 6) & 15, g = idx >> 10;
    int c = s & 31, j = s >> 5;
    int d0 = 2 * (2 * c + j) * 2;        // first of 2 dims: 4c, 4c+1 (j=0) / 4c+2,4c+3 (j=1)
    d0 = (2 * c + j) * 2;                // dim-pair p=2c+j -> dims 2p, 2p+1
    float a0 = 0.f, a1 = 0.f;
#pragma unroll
    for (int b = 0; b < 4; ++b) {
      float e0 = EB[(size_t)(g * 4 + b) * ND + d0];
      float e1 = EB[(size_t)(g * 4 + b) * ND + d0 + 1];
      if (!isfinite(e0)) e0 = 0.f;
      if (!isfinite(e1)) e1 = 0.f;
      float take = (float)((n >> b) & 1);
      a0 += take * e0;
      a1 += take * e1;
    }
    Tu[idx] = f2bf(a0) | (f2bf(a1) << 16);
  }

  // ---- phase 1: pack mask bits (2 points/lane), accumulate cnt terms ----
  const int p0 = chunk * PTS_WG + wave * PTS_WAVE;
  const int* mp = mask + (size_t)o * NM * NP + p0 + 2 * lane;
  int WA = 0, WB = 0;
  float pB = 0.f, TPl = 0.f;
  int2 v[8], u[8];
#pragma unroll
  for (int j = 0; j < 8; ++j) v[j] = *(const int2*)(mp + (size_t)j * NP);
#pragma unroll
  for (int b = 0; b < 4; ++b) {
    if (b < 3) {
#pragma unroll
      for (int j = 0; j < 8; ++j)
        u[j] = *(const int2*)(mp + (size_t)((b + 1) * 8 + j) * NP);
    }
#pragma unroll
    for (int j = 0; j < 8; ++j) {
      const int m = b * 8 + j;
      int bx = (v[j].x != 0), by = (v[j].y != 0);
      WA |= bx << m; WB |= by << m;
      float c = (float)(bx + by);
      TPl += c;
      pB  += esq[m] * c;
    }
    if (b < 3) {
#pragma unroll
      for (int j = 0; j < 8; ++j) v[j] = u[j];
    }
  }
  *(int2*)&Wlds[wave * PTS_WAVE + 2 * lane] = make_int2(WA, WB);
  __syncthreads();

  // ---- phase 2: stream x, 8 pts/iter, prefetch next 8 (4 KB in flight/wave) ----
  const float* xo = net + ((size_t)o * NP + p0) * ND;
  const int half = lane >> 5;           // which point of each pair
  const int c    = lane & 31;           // dim-quad index
  const int dl   = c * 4;               // 4 dims per lane
  const int base = wave * PTS_WAVE;
  float accA = 0.f, accC = 0.f;

  auto comp = [&](const float4 X, const int W) {
    accA += (float)__popc(W) * (X.x * X.x + X.y * X.y + X.z * X.z + X.w * X.w);
    float s0 = 0.f, s1 = 0.f, s2 = 0.f, s3 = 0.f;
#pragma unroll
    for (int g = 0; g < 8; ++g) {
      int n = (W >> (g * 4)) & 15;
      int ix = g * 1024 + n * 64 + c;
      unsigned uA = Tu[ix];
      unsigned uB = Tu[ix + 32];
      s0 += __uint_as_float(uA << 16);
      s1 += __uint_as_float(uA & 0xffff0000u);
      s2 += __uint_as_float(uB << 16);
      s3 += __uint_as_float(uB & 0xffff0000u);
    }
    accC += s0 * X.x + s1 * X.y + s2 * X.z + s3 * X.w;
  };

  float4 Xa0 = *(const float4*)(xo + (size_t)(0 + half) * ND + dl);
  float4 Xa1 = *(const float4*)(xo + (size_t)(2 + half) * ND + dl);
  float4 Xb0 = *(const float4*)(xo + (size_t)(4 + half) * ND + dl);
  float4 Xb1 = *(const float4*)(xo + (size_t)(6 + half) * ND + dl);
  int Wq0 = Wlds[base + 0 + half], Wq1 = Wlds[base + 2 + half];
  int Wq2 = Wlds[base + 4 + half], Wq3 = Wlds[base + 6 + half];

  for (int i = 0; i < PTS_WAVE; i += 8) {
    int pf = i + 8;
    pf = (pf < PTS_WAVE) ? pf : 0;      // last prefetch wraps; values unused
    float4 Ta0 = *(const float4*)(xo + (size_t)(pf + 0 + half) * ND + dl);
    float4 Ta1 = *(const float4*)(xo + (size_t)(pf + 2 + half) * ND + dl);
    float4 Tb0 = *(const float4*)(xo + (size_t)(pf + 4 + half) * ND + dl);
    float4 Tb1 = *(const float4*)(xo + (size_t)(pf + 6 + half) * ND + dl);
    int Tw0 = Wlds[base + pf + 0 + half], Tw1 = Wlds[base + pf + 2 + half];
    int Tw2 = Wlds[base + pf + 4 + half], Tw3 = Wlds[base + pf + 6 + half];

    comp(Xa0, Wq0);
    comp(Xa1, Wq1);
    comp(Xb0, Wq2);
    comp(Xb1, Wq3);

    Xa0 = Ta0; Xa1 = Ta1; Xb0 = Tb0; Xb1 = Tb1;
    Wq0 = Tw0; Wq1 = Tw1; Wq2 = Tw2; Wq3 = Tw3;
  }

  // ---- reduce: wave shfl-xor -> LDS -> block -> global atomics ----
#pragma unroll
  for (int off = 32; off >= 1; off >>= 1) {
    accA += __shfl_xor(accA, off, 64);
    accC += __shfl_xor(accC, off, 64);
    pB   += __shfl_xor(pB,   off, 64);
    TPl  += __shfl_xor(TPl,  off, 64);
  }
  if (lane == 0) {
    red[wave][0] = accA; red[wave][1] = pB;
    red[wave][2] = accC; red[wave][3] = TPl;
  }
  __syncthreads();
  if (tid == 0) {
    float A = 0.f, B = 0.f, C = 0.f, TP = 0.f;
    for (int w = 0; w < 4; ++w) {
      A += red[w][0]; B += red[w][1]; C += red[w][2]; TP += red[w][3];
    }
    atomicAdd(&ws[0], A);
    atomicAdd(&ws[1], B);
    atomicAdd(&ws[2], C);
    atomicAdd(&ws[3], TP);
  }
}

__global__ void distill_final(const float* __restrict__ ws, float* __restrict__ out) {
  float A = ws[0], B = ws[1], C = ws[2], TP = ws[3];
  out[0] = (TP > 0.f) ? (A + B - 2.f * C) / ((float)ND * TP) : 0.f;
}

extern "C" void kernel_launch(void* const* d_in, const int* in_sizes, int n_in,
                              void* d_out, int out_size, void* d_ws, size_t ws_size,
                              hipStream_t stream) {
  const float* net  = (const float*)d_in[0];   // net_out [O*P, D] fp32
  const float* embs = (const float*)d_in[2];   // mask_embs [O*M, D] fp32
  const int*   mask = (const int*)d_in[3];     // mask_pts [O, M, P] int32
  float* ws = (float*)d_ws;

  hipMemsetAsync(d_ws, 0, 4 * sizeof(float), stream);
  distill_main<<<NOBJ * CHUNKS, 256, 0, stream>>>(net, embs, mask, ws);
  distill_final<<<1, 1, 0, stream>>>(ws, (float*)d_out);
}